// Round 8
// baseline (1226.077 us; speedup 1.0000x reference)
//
#include <hip/hip_runtime.h>
#include <cstdint>
#include <cstddef>

typedef __bf16 bf16_t;
typedef __bf16 bf16x8 __attribute__((ext_vector_type(8)));
typedef __bf16 bf16x4 __attribute__((ext_vector_type(4)));
typedef float  f32x4  __attribute__((ext_vector_type(4)));
typedef float  f32x16 __attribute__((ext_vector_type(16)));

#define MFMA16(a, b, c) __builtin_amdgcn_mfma_f32_16x16x32_bf16((a), (b), (c), 0, 0, 0)
#define MFMA32(a, b, c) __builtin_amdgcn_mfma_f32_32x32x16_bf16((a), (b), (c), 0, 0, 0)
#define CVTPK(d, a, b) \
  asm("v_cvt_pk_bf16_f32 %0, %1, %2" : "=v"(d) : "v"(a), "v"(b))
#define PLSWAP(a, b) \
  asm("v_permlane32_swap_b32 %0, %1" : "+v"(a), "+v"(b))

// async global->LDS, 16B per lane. LDS dest must be wave-linear (base + lane*16).
__device__ __forceinline__ void gload_lds16(const bf16_t* g, bf16_t* l) {
  __builtin_amdgcn_global_load_lds(
      (__attribute__((address_space(1))) void*)((void*)g),
      (__attribute__((address_space(3))) void*)l, 16, 0, 0);
}

// ---------------------------------------------------------------------------
// x convert: f32 -> bf16, 4 elems/thread.
// ---------------------------------------------------------------------------
__global__ __launch_bounds__(256) void cvt_f32_bf16(
    const float* __restrict__ in, bf16_t* __restrict__ out, int n) {
  const int i = (blockIdx.x * 256 + threadIdx.x) * 4;
  if (i + 3 < n) {
    const float4 v = *(const float4*)(in + i);
    bf16x4 o;
    o[0] = (bf16_t)v.x; o[1] = (bf16_t)v.y; o[2] = (bf16_t)v.z; o[3] = (bf16_t)v.w;
    *(bf16x4*)(out + i) = o;
  }
}

// ---------------------------------------------------------------------------
// Weight transpose+convert: in f32 [R][C] -> out bf16 [C][R]; R,C mult of 32.
// ---------------------------------------------------------------------------
__global__ __launch_bounds__(256) void transpose_f32_bf16(
    const float* __restrict__ in, bf16_t* __restrict__ out, int R, int C) {
  __shared__ bf16_t tile[32][33];
  const int bc = blockIdx.x * 32, br = blockIdx.y * 32;
  const int tx = threadIdx.x, ty = threadIdx.y;  // (32, 8)
#pragma unroll
  for (int i = 0; i < 32; i += 8)
    tile[ty + i][tx] = (bf16_t)in[(size_t)(br + ty + i) * C + bc + tx];
  __syncthreads();
#pragma unroll
  for (int i = 0; i < 32; i += 8)
    out[(size_t)(bc + ty + i) * R + br + tx] = tile[tx][ty + i];
}

// ---------------------------------------------------------------------------
// GEMM: C[M][N] = A[M][K] @ B[K][N], with Bt given as B^T row-major [N][K].
// 128x128 tile, BK=32, 256 threads = 4 waves (2x2), each wave 64x64 (4x4 frags).
// EPI==0: f32 store to Cout (row stride N) -- final output.
// EPI==1: QKV split epilogue (bf16): Q cols (<2048) pre-scaled by 1/16;
//         cols <4096 -> qk buffer [M][4096]; cols >=4096 (V) -> transposed
//         store vt[(b*8+h)*256+d][2048] at token.
// ---------------------------------------------------------------------------
template <int EPI>
__global__ __launch_bounds__(256) void gemm_bt(
    const bf16_t* __restrict__ A, const bf16_t* __restrict__ Bt,
    void* __restrict__ Cout, bf16_t* __restrict__ Vt, int M, int N, int K) {
  __shared__ __align__(16) bf16_t As[128 * 32];
  __shared__ __align__(16) bf16_t Bs[128 * 32];
  const int tid = threadIdx.x;
  const int lane = tid & 63, w = tid >> 6;
  const int wm = w >> 1, wn = w & 1;
  const int bm = blockIdx.y * 128, bn = blockIdx.x * 128;
  const int l15 = lane & 15, l4 = lane >> 4;

  f32x4 acc[4][4] = {};

  for (int k0 = 0; k0 < K; k0 += 32) {
    __syncthreads();
#pragma unroll
    for (int i = 0; i < 2; ++i) {
      const int idx = i * 256 + tid;
      const int r = idx >> 2, s = idx & 3;
      const int ss = s ^ (r & 3);  // pre-swizzled source seg (XOR involution)
      gload_lds16(A + (size_t)(bm + r) * K + k0 + ss * 8, &As[idx * 8]);
      gload_lds16(Bt + (size_t)(bn + r) * K + k0 + ss * 8, &Bs[idx * 8]);
    }
    __syncthreads();
    bf16x8 af[4], bfr[4];
#pragma unroll
    for (int f = 0; f < 4; ++f) {
      const int ra = wm * 64 + f * 16 + l15;
      const int rb = wn * 64 + f * 16 + l15;
      af[f]  = *(const bf16x8*)&As[ra * 32 + (l4 ^ (ra & 3)) * 8];
      bfr[f] = *(const bf16x8*)&Bs[rb * 32 + (l4 ^ (rb & 3)) * 8];
    }
#pragma unroll
    for (int i = 0; i < 4; ++i)
#pragma unroll
      for (int j = 0; j < 4; ++j) acc[i][j] = MFMA16(af[i], bfr[j], acc[i][j]);
  }

#pragma unroll
  for (int i = 0; i < 4; ++i) {
    const int gr = bm + wm * 64 + i * 16 + l4 * 4;  // 4 consecutive rows gr..gr+3
#pragma unroll
    for (int j = 0; j < 4; ++j) {
      const int gc = bn + wn * 64 + j * 16 + l15;
      if constexpr (EPI == 0) {
        float* C = (float*)Cout;
#pragma unroll
        for (int r = 0; r < 4; ++r)
          C[(size_t)(gr + r) * N + gc] = acc[i][j][r];
      } else {
        bf16_t* C = (bf16_t*)Cout;
        if (gc < 2048) {  // Q region: pre-scale by 1/sqrt(256)
#pragma unroll
          for (int r = 0; r < 4; ++r)
            C[(size_t)(gr + r) * 4096 + gc] = (bf16_t)(acc[i][j][r] * 0.0625f);
        } else if (gc < 4096) {  // K region
#pragma unroll
          for (int r = 0; r < 4; ++r)
            C[(size_t)(gr + r) * 4096 + gc] = (bf16_t)acc[i][j][r];
        } else {  // V region: write transposed vt[(b*8+h)*256+d][2048]
          const int c = gc - 4096, h = c >> 8, d = c & 255;
          const int b = gr >> 11, lt = gr & 2047;
          bf16x4 pk;
#pragma unroll
          for (int r = 0; r < 4; ++r) pk[r] = (bf16_t)acc[i][j][r];
          *(bf16x4*)&Vt[((size_t)(b * 8 + h) * 256 + d) * 2048 + lt] = pk;
        }
      }
    }
  }
}

// ---------------------------------------------------------------------------
// Flash attention, 32x32 MFMA, in-register P, double-Q per wave.
// Each wave owns 64 q-cols (two sets A/B) so every K/V LDS fragment read
// feeds TWO MFMAs (1 read : 2 MFMA) -- halves CU LDS-port traffic vs R7.
// 1 wave/SIMD (launch_bounds(256,1), ~450 unified regs). KVBLK=32, LDS 64KB,
// double-buffered via global_load_lds + counted vmcnt(8).
// Grid: 256 blocks (XCD-swizzled) = 8 q-tiles x 32 bh; block = 4 waves x 64 q.
// ---------------------------------------------------------------------------
__global__ __launch_bounds__(256, 1) void attn_fwd(
    const bf16_t* __restrict__ qk, const bf16_t* __restrict__ vt,
    bf16_t* __restrict__ ao) {
  __shared__ __align__(16) bf16_t Ks[2][32 * 256];   // 2 x 16KB
  __shared__ __align__(16) bf16_t Vs[2][256 * 32];   // 2 x 16KB
  const int tid = threadIdx.x, lane = tid & 63, w = tid >> 6;
  const int l31 = lane & 31, h5 = lane >> 5;
  const int p4 = l31 & 15, pv2 = (l31 >> 1) & 3;
  // XCD swizzle: 256 blocks, chunk 32 per XCD
  const int bid = blockIdx.x;
  const int swz = (bid & 7) * 32 + (bid >> 3);
  const int qt = swz & 7;           // 8 q-tiles of 256 rows
  const int bh = swz >> 3;          // 32 (b,h) pairs
  const int bb = bh >> 3, hh = bh & 7;

  // Q fragments (B-operand), two sets: qcolA = base+l31, qcolB = +32
  const int qcolA = qt * 256 + w * 64 + l31;
  const bf16_t* qbaseA =
      qk + (size_t)(bb * 2048 + qcolA) * 4096 + hh * 256 + h5 * 8;
  bf16x8 qfA[16], qfB[16];
#pragma unroll
  for (int s = 0; s < 16; ++s) {
    qfA[s] = *(const bf16x8*)(qbaseA + s * 16);
    qfB[s] = *(const bf16x8*)(qbaseA + (size_t)32 * 4096 + s * 16);
  }

  const bf16_t* kg = qk + (size_t)(bb * 2048) * 4096 + 2048 + hh * 256;
  const bf16_t* vg = vt + (size_t)bh * 256 * 2048;

#define STAGE_TILES(bufidx, tile)                                           \
  {                                                                         \
    const int t32 = (tile) * 32;                                            \
    _Pragma("unroll") for (int c = 0; c < 4; ++c) {                         \
      const int idx = c * 256 + tid;                                        \
      const int kr = idx >> 5, kse = idx & 31;                              \
      gload_lds16(kg + (size_t)(t32 + kr) * 4096 + ((kse ^ (kr & 15)) * 8), \
                  &Ks[bufidx][idx * 8]);                                    \
    }                                                                       \
    _Pragma("unroll") for (int c = 0; c < 4; ++c) {                         \
      const int idx = c * 256 + tid;                                        \
      const int vr = idx >> 2, vse = idx & 3;                               \
      gload_lds16(vg + (size_t)vr * 2048 + t32 +                            \
                      ((vse ^ ((vr >> 1) & 3)) * 8),                        \
                  &Vs[bufidx][idx * 8]);                                    \
    }                                                                       \
  }

  STAGE_TILES(0, 0);
  STAGE_TILES(1, 1);

  f32x16 oA[8] = {}, oB[8] = {};
  float mA = -1e30f, lsA = 0.f, mB = -1e30f, lsB = 0.f;

  for (int kv = 0; kv < 64; ++kv) {
    const int cur = kv & 1;
    asm volatile("s_waitcnt vmcnt(8)" ::: "memory");  // tile kv complete
    __builtin_amdgcn_s_barrier();
    __builtin_amdgcn_sched_barrier(0);
    const bf16_t* Kc = Ks[cur];
    const bf16_t* Vc = Vs[cur];

    // ---- S^T = K @ Q^T: one kf read feeds both q-sets ----
    f32x16 saA = {}, saB = {};
    __builtin_amdgcn_s_setprio(1);
#pragma unroll
    for (int s = 0; s < 16; ++s) {
      bf16x8 kf = *(const bf16x8*)
          ((const char*)Kc + l31 * 512 + (((2 * s + h5) ^ p4) << 4));
      saA = MFMA32(kf, qfA[s], saA);
      saB = MFMA32(kf, qfB[s], saB);
    }
    __builtin_amdgcn_s_setprio(0);

    // ---- online softmax, defer-max THR=8, per q-set ----
#define SOFTMAX_SET(SA, M_, LS_, O_)                                        \
    {                                                                       \
      float pm = SA[0];                                                     \
      _Pragma("unroll") for (int r = 1; r < 16; ++r) pm = fmaxf(pm, SA[r]); \
      pm = fmaxf(pm, __shfl_xor(pm, 32));                                   \
      if (!__all(pm <= M_ + 8.0f)) {                                        \
        const float mn = fmaxf(M_, pm);                                     \
        const float al = __expf(M_ - mn);                                   \
        M_ = mn;                                                            \
        LS_ *= al;                                                          \
        _Pragma("unroll") for (int dt = 0; dt < 8; ++dt)                    \
          _Pragma("unroll") for (int r = 0; r < 16; ++r) O_[dt][r] *= al;   \
      }                                                                     \
      float rs = 0.f;                                                       \
      _Pragma("unroll") for (int r = 0; r < 16; ++r) {                      \
        SA[r] = __expf(SA[r] - M_); rs += SA[r];                            \
      }                                                                     \
      rs += __shfl_xor(rs, 32);                                             \
      LS_ += rs;                                                            \
    }
    SOFTMAX_SET(saA, mA, lsA, oA);
    SOFTMAX_SET(saB, mB, lsB, oB);

    // ---- P-frags in regs + PV: one vf read feeds both q-sets ----
#define MAKE_PU(SA, c0, PU)                                                 \
    {                                                                       \
      unsigned w0, w1, w2, w3;                                              \
      CVTPK(w0, SA[4 * (c0) + 0], SA[4 * (c0) + 1]);                        \
      CVTPK(w2, SA[4 * (c0) + 4], SA[4 * (c0) + 5]);                        \
      PLSWAP(w0, w2);                                                       \
      CVTPK(w1, SA[4 * (c0) + 2], SA[4 * (c0) + 3]);                        \
      CVTPK(w3, SA[4 * (c0) + 6], SA[4 * (c0) + 7]);                        \
      PLSWAP(w1, w3);                                                       \
      PU.u[0] = w0; PU.u[1] = w1; PU.u[2] = w2; PU.u[3] = w3;               \
    }
    __builtin_amdgcn_s_setprio(1);
#pragma unroll
    for (int s2 = 0; s2 < 2; ++s2) {
      union { unsigned u[4]; bf16x8 v; } puA, puB;
      MAKE_PU(saA, 2 * s2, puA);
      MAKE_PU(saB, 2 * s2, puB);
#pragma unroll
      for (int dt = 0; dt < 8; ++dt) {
        bf16x8 vf = *(const bf16x8*)((const char*)Vc +
            (dt * 32 + l31) * 64 + (((s2 * 2 + h5) ^ pv2) << 4));
        oA[dt] = MFMA32(vf, puA.v, oA[dt]);
        oB[dt] = MFMA32(vf, puB.v, oB[dt]);
      }
    }
    __builtin_amdgcn_s_setprio(0);

    __builtin_amdgcn_sched_barrier(0);
    __builtin_amdgcn_s_barrier();     // all waves done reading buf[cur]
    __builtin_amdgcn_sched_barrier(0);
    STAGE_TILES(cur, (kv + 2) & 63);  // prefetch (wraps harmlessly at end)
  }

  // ---- epilogue: normalize, store O^T -> ao[token][hh*256 + d] ----
  const float invA = 1.0f / lsA, invB = 1.0f / lsB;
  bf16_t* aorA = ao + (size_t)(bb * 2048 + qcolA) * 2048 + hh * 256 + 4 * h5;
  bf16_t* aorB = aorA + (size_t)32 * 2048;
#pragma unroll
  for (int dt = 0; dt < 8; ++dt)
#pragma unroll
    for (int c = 0; c < 4; ++c) {
      bf16x4 ovA, ovB;
#pragma unroll
      for (int bq = 0; bq < 4; ++bq) {
        ovA[bq] = (bf16_t)(oA[dt][4 * c + bq] * invA);
        ovB[bq] = (bf16_t)(oB[dt][4 * c + bq] * invB);
      }
      *(bf16x4*)(aorA + dt * 32 + 8 * c) = ovA;
      *(bf16x4*)(aorB + dt * 32 + 8 * c) = ovB;
    }
}

// ---------------------------------------------------------------------------
extern "C" void kernel_launch(void* const* d_in, const int* in_sizes, int n_in,
                              void* d_out, int out_size, void* d_ws,
                              size_t ws_size, hipStream_t stream) {
  (void)in_sizes; (void)n_in; (void)out_size; (void)ws_size;
  const float* x    = (const float*)d_in[0];  // [8192][256] f32
  const float* wqkv = (const float*)d_in[1];  // [256][6144] f32
  const float* wout = (const float*)d_in[2];  // [2048][256] f32
  float* out = (float*)d_out;                 // [8192][256] f32

  char* ws = (char*)d_ws;
  bf16_t* xb  = (bf16_t*)(ws);                            // [8192][256]   4.2MB
  bf16_t* wqt = (bf16_t*)(ws + 4194304);                  // [6144][256]   3.1MB
  bf16_t* wot = (bf16_t*)(ws + 7340032);                  // [256][2048]   1.0MB
  bf16_t* qkb = (bf16_t*)(ws + 8388608);                  // [8192][4096]  67MB
  bf16_t* vtb = (bf16_t*)(ws + 8388608 + 67108864);       // [32][256][2048] 33.6MB
  bf16_t* aob = (bf16_t*)(ws + 8388608 + 67108864 + 33554432);  // [8192][2048] 33.6MB

  cvt_f32_bf16<<<2048, 256, 0, stream>>>(x, xb, 8192 * 256);
  transpose_f32_bf16<<<dim3(192, 8), dim3(32, 8), 0, stream>>>(wqkv, wqt, 256, 6144);
  transpose_f32_bf16<<<dim3(8, 64), dim3(32, 8), 0, stream>>>(wout, wot, 2048, 256);
  // qkv = x @ W_qkv, split epilogue (Q pre-scaled; Q,K row-major; V transposed)
  gemm_bt<1><<<dim3(48, 64), 256, 0, stream>>>(xb, wqt, qkb, vtb, 8192, 6144, 256);
  // attention
  attn_fwd<<<256, 256, 0, stream>>>(qkb, vtb, aob);
  // out = attn_out @ W_out (f32 store)
  gemm_bt<0><<<dim3(2, 64), 256, 0, stream>>>(aob, wot, out, nullptr, 8192, 256, 2048);
}

// Round 9
// 367.358 us; speedup vs baseline: 3.3376x; 3.3376x over previous
//
#include <hip/hip_runtime.h>
#include <cstdint>
#include <cstddef>

typedef __bf16 bf16_t;
typedef __bf16 bf16x8 __attribute__((ext_vector_type(8)));
typedef __bf16 bf16x4 __attribute__((ext_vector_type(4)));
typedef float  f32x4  __attribute__((ext_vector_type(4)));
typedef float  f32x16 __attribute__((ext_vector_type(16)));

#define MFMA16(a, b, c) __builtin_amdgcn_mfma_f32_16x16x32_bf16((a), (b), (c), 0, 0, 0)
#define MFMA32(a, b, c) __builtin_amdgcn_mfma_f32_32x32x16_bf16((a), (b), (c), 0, 0, 0)
#define CVTPK(d, a, b) \
  asm("v_cvt_pk_bf16_f32 %0, %1, %2" : "=v"(d) : "v"(a), "v"(b))
#define PLSWAP(a, b) \
  asm("v_permlane32_swap_b32 %0, %1" : "+v"(a), "+v"(b))

// async global->LDS, 16B per lane. LDS dest must be wave-linear (base + lane*16).
__device__ __forceinline__ void gload_lds16(const bf16_t* g, bf16_t* l) {
  __builtin_amdgcn_global_load_lds(
      (__attribute__((address_space(1))) void*)((void*)g),
      (__attribute__((address_space(3))) void*)l, 16, 0, 0);
}

// ---------------------------------------------------------------------------
// x convert: f32 -> bf16, 4 elems/thread.
// ---------------------------------------------------------------------------
__global__ __launch_bounds__(256) void cvt_f32_bf16(
    const float* __restrict__ in, bf16_t* __restrict__ out, int n) {
  const int i = (blockIdx.x * 256 + threadIdx.x) * 4;
  if (i + 3 < n) {
    const float4 v = *(const float4*)(in + i);
    bf16x4 o;
    o[0] = (bf16_t)v.x; o[1] = (bf16_t)v.y; o[2] = (bf16_t)v.z; o[3] = (bf16_t)v.w;
    *(bf16x4*)(out + i) = o;
  }
}

// ---------------------------------------------------------------------------
// Weight transpose+convert: in f32 [R][C] -> out bf16 [C][R]; R,C mult of 32.
// ---------------------------------------------------------------------------
__global__ __launch_bounds__(256) void transpose_f32_bf16(
    const float* __restrict__ in, bf16_t* __restrict__ out, int R, int C) {
  __shared__ bf16_t tile[32][33];
  const int bc = blockIdx.x * 32, br = blockIdx.y * 32;
  const int tx = threadIdx.x, ty = threadIdx.y;  // (32, 8)
#pragma unroll
  for (int i = 0; i < 32; i += 8)
    tile[ty + i][tx] = (bf16_t)in[(size_t)(br + ty + i) * C + bc + tx];
  __syncthreads();
#pragma unroll
  for (int i = 0; i < 32; i += 8)
    out[(size_t)(bc + ty + i) * R + br + tx] = tile[tx][ty + i];
}

// ---------------------------------------------------------------------------
// GEMM: C[M][N] = A[M][K] @ B[K][N], with Bt given as B^T row-major [N][K].
// 128x128 tile, BK=32, 256 threads = 4 waves (2x2), each wave 64x64 (4x4 frags).
// EPI==0: f32 store to Cout (row stride N) -- final output.
// EPI==1: QKV split epilogue (bf16): Q cols (<2048) pre-scaled by 1/16;
//         cols <4096 -> qk buffer [M][4096]; cols >=4096 (V) -> transposed
//         store vt[(b*8+h)*256+d][2048] at token.
// ---------------------------------------------------------------------------
template <int EPI>
__global__ __launch_bounds__(256) void gemm_bt(
    const bf16_t* __restrict__ A, const bf16_t* __restrict__ Bt,
    void* __restrict__ Cout, bf16_t* __restrict__ Vt, int M, int N, int K) {
  __shared__ __align__(16) bf16_t As[128 * 32];
  __shared__ __align__(16) bf16_t Bs[128 * 32];
  const int tid = threadIdx.x;
  const int lane = tid & 63, w = tid >> 6;
  const int wm = w >> 1, wn = w & 1;
  const int bm = blockIdx.y * 128, bn = blockIdx.x * 128;
  const int l15 = lane & 15, l4 = lane >> 4;

  f32x4 acc[4][4] = {};

  for (int k0 = 0; k0 < K; k0 += 32) {
    __syncthreads();
#pragma unroll
    for (int i = 0; i < 2; ++i) {
      const int idx = i * 256 + tid;
      const int r = idx >> 2, s = idx & 3;
      const int ss = s ^ (r & 3);  // pre-swizzled source seg (XOR involution)
      gload_lds16(A + (size_t)(bm + r) * K + k0 + ss * 8, &As[idx * 8]);
      gload_lds16(Bt + (size_t)(bn + r) * K + k0 + ss * 8, &Bs[idx * 8]);
    }
    __syncthreads();
    bf16x8 af[4], bfr[4];
#pragma unroll
    for (int f = 0; f < 4; ++f) {
      const int ra = wm * 64 + f * 16 + l15;
      const int rb = wn * 64 + f * 16 + l15;
      af[f]  = *(const bf16x8*)&As[ra * 32 + (l4 ^ (ra & 3)) * 8];
      bfr[f] = *(const bf16x8*)&Bs[rb * 32 + (l4 ^ (rb & 3)) * 8];
    }
#pragma unroll
    for (int i = 0; i < 4; ++i)
#pragma unroll
      for (int j = 0; j < 4; ++j) acc[i][j] = MFMA16(af[i], bfr[j], acc[i][j]);
  }

#pragma unroll
  for (int i = 0; i < 4; ++i) {
    const int gr = bm + wm * 64 + i * 16 + l4 * 4;  // 4 consecutive rows gr..gr+3
#pragma unroll
    for (int j = 0; j < 4; ++j) {
      const int gc = bn + wn * 64 + j * 16 + l15;
      if constexpr (EPI == 0) {
        float* C = (float*)Cout;
#pragma unroll
        for (int r = 0; r < 4; ++r)
          C[(size_t)(gr + r) * N + gc] = acc[i][j][r];
      } else {
        bf16_t* C = (bf16_t*)Cout;
        if (gc < 2048) {  // Q region: pre-scale by 1/sqrt(256)
#pragma unroll
          for (int r = 0; r < 4; ++r)
            C[(size_t)(gr + r) * 4096 + gc] = (bf16_t)(acc[i][j][r] * 0.0625f);
        } else if (gc < 4096) {  // K region
#pragma unroll
          for (int r = 0; r < 4; ++r)
            C[(size_t)(gr + r) * 4096 + gc] = (bf16_t)acc[i][j][r];
        } else {  // V region: write transposed vt[(b*8+h)*256+d][2048]
          const int c = gc - 4096, h = c >> 8, d = c & 255;
          const int b = gr >> 11, lt = gr & 2047;
          bf16x4 pk;
#pragma unroll
          for (int r = 0; r < 4; ++r) pk[r] = (bf16_t)acc[i][j][r];
          *(bf16x4*)&Vt[((size_t)(b * 8 + h) * 256 + d) * 2048 + lt] = pk;
        }
      }
    }
  }
}

// ---------------------------------------------------------------------------
// Flash attention, R7 base + T15 pipeline: QK of tile t+1 issued BEFORE
// softmax of tile t, so softmax VALU overlaps the MFMA drain. K/V staging
// split: K(t+2) staged at phase start (Ks[t&1] free after QK_t last iter),
// V(t+2) staged after end barrier (Vs[t&1] free after PV_t). Counted
// vmcnt(4): one V stage-group always in flight.
// KVBLK=32, LDS 64KB, 2 blocks/CU. Grid: 512 blocks (XCD-swizzled) =
// 16 q-tiles x 32 bh. Block 256 = 4 waves; wave owns 32 q-cols, d=256.
// ---------------------------------------------------------------------------
__global__ __launch_bounds__(256, 2) void attn_fwd(
    const bf16_t* __restrict__ qk, const bf16_t* __restrict__ vt,
    bf16_t* __restrict__ ao) {
  __shared__ __align__(16) bf16_t Ks[2][32 * 256];   // 2 x 16KB
  __shared__ __align__(16) bf16_t Vs[2][256 * 32];   // 2 x 16KB
  const int tid = threadIdx.x, lane = tid & 63, w = tid >> 6;
  const int l31 = lane & 31, h5 = lane >> 5;
  const int p4 = l31 & 15, pv2 = (l31 >> 1) & 3;
  // XCD swizzle: 512 blocks, chunk 64 per XCD (4 bh per XCD L2)
  const int bid = blockIdx.x;
  const int swz = (bid & 7) * 64 + (bid >> 3);
  const int qt = swz & 15;          // 16 q-tiles of 128 rows
  const int bh = swz >> 4;          // 32 (b,h) pairs
  const int bb = bh >> 3, hh = bh & 7;

  // Q fragments (B-operand): lane holds Q[q = qcol][d = s*16 + h5*8 + j]
  const int qcol = qt * 128 + w * 32 + l31;
  const bf16_t* qbase =
      qk + (size_t)(bb * 2048 + qcol) * 4096 + hh * 256 + h5 * 8;
  bf16x8 qf[16];
#pragma unroll
  for (int s = 0; s < 16; ++s) qf[s] = *(const bf16x8*)(qbase + s * 16);

  const bf16_t* kg = qk + (size_t)(bb * 2048) * 4096 + 2048 + hh * 256;
  const bf16_t* vg = vt + (size_t)bh * 256 * 2048;

#define STAGE_K(bufidx, tile)                                               \
  {                                                                         \
    const int t32k = (tile) * 32;                                           \
    _Pragma("unroll") for (int c = 0; c < 4; ++c) {                         \
      const int idx = c * 256 + tid;                                        \
      const int kr = idx >> 5, kse = idx & 31;                              \
      gload_lds16(kg + (size_t)(t32k + kr) * 4096 + ((kse ^ (kr & 15)) * 8),\
                  &Ks[bufidx][idx * 8]);                                    \
    }                                                                       \
  }
#define STAGE_V(bufidx, tile)                                               \
  {                                                                         \
    const int t32v = (tile) * 32;                                           \
    _Pragma("unroll") for (int c = 0; c < 4; ++c) {                         \
      const int idx = c * 256 + tid;                                        \
      const int vr = idx >> 2, vse = idx & 3;                               \
      gload_lds16(vg + (size_t)vr * 2048 + t32v +                           \
                      ((vse ^ ((vr >> 1) & 3)) * 8),                        \
                  &Vs[bufidx][idx * 8]);                                    \
    }                                                                       \
  }

#define ZERO16(v) \
  { _Pragma("unroll") for (int z = 0; z < 16; ++z) (v)[z] = 0.f; }

#define QK_PHASE(SN, KB)                                                    \
  {                                                                         \
    __builtin_amdgcn_s_setprio(1);                                          \
    _Pragma("unroll") for (int s = 0; s < 16; ++s) {                        \
      bf16x8 kf = *(const bf16x8*)((const char*)Ks[KB] + l31 * 512 +        \
                                   (((2 * s + h5) ^ p4) << 4));             \
      SN = MFMA32(kf, qf[s], SN);                                           \
    }                                                                       \
    __builtin_amdgcn_s_setprio(0);                                          \
  }

#define SOFTMAX_SET(SA)                                                     \
    {                                                                       \
      float pm = SA[0];                                                     \
      _Pragma("unroll") for (int r = 1; r < 16; ++r) pm = fmaxf(pm, SA[r]); \
      pm = fmaxf(pm, __shfl_xor(pm, 32));                                   \
      if (!__all(pm <= m + 8.0f)) {  /* defer-max THR=8 */                  \
        const float mn = fmaxf(m, pm);                                      \
        const float al = __expf(m - mn);                                    \
        m = mn;                                                             \
        lsum *= al;                                                         \
        _Pragma("unroll") for (int dt = 0; dt < 8; ++dt)                    \
          _Pragma("unroll") for (int r = 0; r < 16; ++r) o[dt][r] *= al;    \
      }                                                                     \
      float rs = 0.f;                                                       \
      _Pragma("unroll") for (int r = 0; r < 16; ++r) {                      \
        SA[r] = __expf(SA[r] - m); rs += SA[r];                             \
      }                                                                     \
      rs += __shfl_xor(rs, 32);                                             \
      lsum += rs;                                                           \
    }

#define MAKE_PU(SA, c0, PU)                                                 \
    {                                                                       \
      unsigned w0, w1, w2, w3;                                              \
      CVTPK(w0, SA[4 * (c0) + 0], SA[4 * (c0) + 1]);                        \
      CVTPK(w2, SA[4 * (c0) + 4], SA[4 * (c0) + 5]);                        \
      PLSWAP(w0, w2);                                                       \
      CVTPK(w1, SA[4 * (c0) + 2], SA[4 * (c0) + 3]);                        \
      CVTPK(w3, SA[4 * (c0) + 6], SA[4 * (c0) + 7]);                        \
      PLSWAP(w1, w3);                                                       \
      PU.u[0] = w0; PU.u[1] = w1; PU.u[2] = w2; PU.u[3] = w3;               \
    }

#define PV_PHASE(SA, VB)                                                    \
  {                                                                         \
    __builtin_amdgcn_s_setprio(1);                                          \
    _Pragma("unroll") for (int s2 = 0; s2 < 2; ++s2) {                      \
      union { unsigned u[4]; bf16x8 v; } pu;                                \
      MAKE_PU(SA, 2 * s2, pu);                                              \
      _Pragma("unroll") for (int dt = 0; dt < 8; ++dt) {                    \
        bf16x8 vf = *(const bf16x8*)((const char*)Vs[VB] +                  \
            (dt * 32 + l31) * 64 + (((s2 * 2 + h5) ^ pv2) << 4));           \
        o[dt] = MFMA32(vf, pu.v, o[dt]);                                    \
      }                                                                     \
    }                                                                       \
    __builtin_amdgcn_s_setprio(0);                                          \
  }

// BODY(tile t): finish tile t (softmax+PV on SP), start QK_{t+1} into SN.
// CURB = t&1, NXTB = (t+1)&1.
#define BODY(SP, SN, CURB, NXTB, KVT)                                       \
  {                                                                         \
    asm volatile("s_waitcnt vmcnt(4)" ::: "memory");                        \
    __builtin_amdgcn_s_barrier();                                           \
    __builtin_amdgcn_sched_barrier(0);                                      \
    STAGE_K(CURB, ((KVT) + 2) & 63);                                        \
    QK_PHASE(SN, NXTB);                                                     \
    SOFTMAX_SET(SP);                                                        \
    PV_PHASE(SP, CURB);                                                     \
    __builtin_amdgcn_sched_barrier(0);                                      \
    __builtin_amdgcn_s_barrier();                                           \
    __builtin_amdgcn_sched_barrier(0);                                      \
    STAGE_V(CURB, ((KVT) + 2) & 63);                                        \
  }

  // prologue: stage tiles 0,1 (order K0,V0,K1,V1 for vmcnt accounting)
  STAGE_K(0, 0); STAGE_V(0, 0); STAGE_K(1, 1); STAGE_V(1, 1);

  f32x16 o[8] = {};
  float m = -1e30f, lsum = 0.f;
  f32x16 saA, saB;
  ZERO16(saA); ZERO16(saB);

  asm volatile("s_waitcnt vmcnt(12)" ::: "memory");  // K0 retired
  __builtin_amdgcn_s_barrier();
  __builtin_amdgcn_sched_barrier(0);
  QK_PHASE(saA, 0);  // QK_0

  for (int kv = 0; kv < 64; kv += 2) {
    BODY(saA, saB, 0, 1, kv);      // tile kv   (even): K in Ks[0], V in Vs[0]
    ZERO16(saA);
    BODY(saB, saA, 1, 0, kv + 1);  // tile kv+1 (odd)
    ZERO16(saB);
  }
  // saA holds QK of wrapped tile 64 -- discarded.

  // ---- epilogue: normalize, store O^T -> ao[token][hh*256 + d] ----
  const float inv = 1.0f / lsum;
  bf16_t* aor = ao + (size_t)(bb * 2048 + qcol) * 2048 + hh * 256 + 4 * h5;
#pragma unroll
  for (int dt = 0; dt < 8; ++dt)
#pragma unroll
    for (int c = 0; c < 4; ++c) {
      bf16x4 ov;
#pragma unroll
      for (int bq = 0; bq < 4; ++bq) ov[bq] = (bf16_t)(o[dt][4 * c + bq] * inv);
      *(bf16x4*)(aor + dt * 32 + 8 * c) = ov;
    }
}

// ---------------------------------------------------------------------------
extern "C" void kernel_launch(void* const* d_in, const int* in_sizes, int n_in,
                              void* d_out, int out_size, void* d_ws,
                              size_t ws_size, hipStream_t stream) {
  (void)in_sizes; (void)n_in; (void)out_size; (void)ws_size;
  const float* x    = (const float*)d_in[0];  // [8192][256] f32
  const float* wqkv = (const float*)d_in[1];  // [256][6144] f32
  const float* wout = (const float*)d_in[2];  // [2048][256] f32
  float* out = (float*)d_out;                 // [8192][256] f32

  char* ws = (char*)d_ws;
  bf16_t* xb  = (bf16_t*)(ws);                            // [8192][256]   4.2MB
  bf16_t* wqt = (bf16_t*)(ws + 4194304);                  // [6144][256]   3.1MB
  bf16_t* wot = (bf16_t*)(ws + 7340032);                  // [256][2048]   1.0MB
  bf16_t* qkb = (bf16_t*)(ws + 8388608);                  // [8192][4096]  67MB
  bf16_t* vtb = (bf16_t*)(ws + 8388608 + 67108864);       // [32][256][2048] 33.6MB
  bf16_t* aob = (bf16_t*)(ws + 8388608 + 67108864 + 33554432);  // [8192][2048] 33.6MB

  cvt_f32_bf16<<<2048, 256, 0, stream>>>(x, xb, 8192 * 256);
  transpose_f32_bf16<<<dim3(192, 8), dim3(32, 8), 0, stream>>>(wqkv, wqt, 256, 6144);
  transpose_f32_bf16<<<dim3(8, 64), dim3(32, 8), 0, stream>>>(wout, wot, 2048, 256);
  // qkv = x @ W_qkv, split epilogue (Q pre-scaled; Q,K row-major; V transposed)
  gemm_bt<1><<<dim3(48, 64), 256, 0, stream>>>(xb, wqt, qkb, vtb, 8192, 6144, 256);
  // attention
  attn_fwd<<<512, 256, 0, stream>>>(qkb, vtb, aob);
  // out = attn_out @ W_out (f32 store)
  gemm_bt<0><<<dim3(2, 64), 256, 0, stream>>>(aob, wot, out, nullptr, 8192, 256, 2048);
}